// Round 8
// baseline (769.993 us; speedup 1.0000x reference)
//
#include <hip/hip_runtime.h>
#include <hip/hip_bf16.h>

#define DIV_UP(a,b) (((a)+(b)-1)/(b))

typedef __attribute__((ext_vector_type(8))) short short8v;
typedef __attribute__((ext_vector_type(4))) float f32x4;

__device__ inline unsigned short f2bf(float f){
  unsigned u = __float_as_uint(f);
  u += 0x7FFFu + ((u >> 16) & 1u);          // RNE
  return (unsigned short)(u >> 16);
}
__device__ inline float bf2f(unsigned short h){ return __uint_as_float(((unsigned)h) << 16); }

// ---------------- preprocessing ----------------
// k_count also emits rank[e] = position of edge e within its dst row -> k_fill needs no atomics.
__global__ __launch_bounds__(256) void k_count(const int* __restrict__ dst, int* __restrict__ counts,
                                               int* __restrict__ rank, int E){
  int e = blockIdx.x*256 + threadIdx.x;
  if (e < E){
    int d = dst[e];
    rank[e] = atomicAdd(&counts[d], 1);
  }
}

__global__ __launch_bounds__(1024) void k_scan1(const int* __restrict__ counts, int* __restrict__ rowptr,
                                                int* __restrict__ bsum, float* __restrict__ dinv, int N){
  __shared__ int s[1024];
  int t = threadIdx.x, g = blockIdx.x*1024 + t;
  int v = (g < N) ? counts[g] : 0;
  if (g < N) dinv[g] = rsqrtf((float)(v + 1));   // +1 = self-loop
  s[t] = v; __syncthreads();
  for (int off = 1; off < 1024; off <<= 1){
    int u = (t >= off) ? s[t-off] : 0; __syncthreads();
    s[t] += u; __syncthreads();
  }
  if (g < N) rowptr[g] = s[t] - v;
  if (t == 1023) bsum[blockIdx.x] = s[1023];
}

__global__ __launch_bounds__(128) void k_scan2(const int* __restrict__ bsum, int* __restrict__ boff,
                                               int nb, int* __restrict__ rowptr, int N){
  __shared__ int s[128];
  int t = threadIdx.x;
  int v = (t < nb) ? bsum[t] : 0;
  s[t] = v; __syncthreads();
  for (int off = 1; off < 128; off <<= 1){
    int u = (t >= off) ? s[t-off] : 0; __syncthreads();
    s[t] += u; __syncthreads();
  }
  if (t < nb) boff[t] = s[t] - v;
  if (t == 127) rowptr[N] = s[127];
}

__global__ __launch_bounds__(1024) void k_scan3(int* __restrict__ rowptr, const int* __restrict__ boff, int N){
  int g = blockIdx.x*1024 + threadIdx.x;
  if (g < N) rowptr[g] += boff[blockIdx.x];
}

// XCD-grouped CSR fill (atomic-free via rank): group g writes only its N/8 dst slice.
__global__ __launch_bounds__(256) void k_fill_g(const int* __restrict__ src, const int* __restrict__ dst,
                                                const int* __restrict__ rank, const int* __restrict__ rowptr,
                                                int* __restrict__ csr, int E, int N){
  const int g   = blockIdx.x & 7;
  const int bi  = blockIdx.x >> 3;
  const int bpg = gridDim.x >> 3;
  const int chunk = (N + 7) >> 3;
  const int lo = g*chunk;
  const int hi = min(lo + chunk, N);
  for (int e = bi*256 + threadIdx.x; e < E; e += bpg*256){
    int d = dst[e];
    if (d >= lo && d < hi) csr[rowptr[d] + rank[e]] = src[e];
  }
}

// ---------------- split weights into FRAGMENT-LINEARIZED bf16 hi/lo ----------------
__global__ __launch_bounds__(256) void k_split_w(const float* __restrict__ W1, const float* __restrict__ W2,
                                                 unsigned short* __restrict__ W1h, unsigned short* __restrict__ W1l,
                                                 unsigned short* __restrict__ W2h, unsigned short* __restrict__ W2l,
                                                 int L){
  int idx = blockIdx.x*256 + threadIdx.x;
  int n1 = 64*128;
  if (idx < n1){
    int j = idx & 7, lane = (idx >> 3) & 63, t = idx >> 9;   // t = kc*8+nt, kc<2 (K=64)
    int kc = t >> 3, nt = t & 7;
    int tcol = lane & 15, quad = lane >> 4;
    int k = kc*32 + quad*8 + j, n = nt*16 + tcol;
    float v = W1[k*128 + n];
    unsigned short hi = f2bf(v);
    W1h[idx] = hi; W1l[idx] = f2bf(v - bf2f(hi));
  } else {
    int idx2 = idx - n1;
    if (idx2 >= L*128*128) return;
    int i = idx2 >> 14, r = idx2 & 16383;
    int j = r & 7, lane = (r >> 3) & 63, t = r >> 9;         // t = kc*8+nt, kc<4 (K=128)
    int kc = t >> 3, nt = t & 7;
    int tcol = lane & 15, quad = lane >> 4;
    int k = kc*32 + quad*8 + j, n = nt*16 + tcol;
    float v = W2[(size_t)i*16384 + k*128 + n];
    unsigned short hi = f2bf(v);
    W2h[idx2] = hi; W2l[idx2] = f2bf(v - bf2f(hi));
  }
}

// ---------------- fused layer 1: gather(x) -> GEMM(W1,b1,relu) -> GEMM(W2_0)*dinv -> pF ----------------
__global__ __launch_bounds__(256) void k_fuse1(const float* __restrict__ x, const int* __restrict__ rowptr,
                                               const int* __restrict__ csr, const float* __restrict__ dinv,
                                               const unsigned short* __restrict__ W1h, const unsigned short* __restrict__ W1l,
                                               const float* __restrict__ b1,
                                               const unsigned short* __restrict__ W2h0, const unsigned short* __restrict__ W2l0,
                                               float* __restrict__ pout, int N){
  __shared__ unsigned short Xh[64][88],  Xl[64][88];    // stride 88: 176B=11x16B, 2-way banks
  __shared__ unsigned short Hh[64][168], Hl[64][168];   // stride 168: 336B=21x16B, 2-way banks
  const int tid = threadIdx.x;
  const int node0 = blockIdx.x*64;

  // phase 1: gather raw x with dinv weights (16 lanes/node, 4 iters of 16 nodes)
  {
    const int nl = tid >> 4;
    const int c  = (tid & 15) * 4;
    const float* xc = x + c;
    for (int it = 0; it < 4; ++it){
      int ln = it*16 + nl;
      int node = node0 + ln;
      if (node < N){
        const float dn = dinv[node];
        float4 s = *(const float4*)(x + (size_t)node*64 + c);
        float ax = dn*s.x, ay = dn*s.y, az = dn*s.z, aw = dn*s.w;
        int e = rowptr[node], end = rowptr[node+1];
        for (; e + 4 <= end; e += 4){
          int s0 = csr[e], s1 = csr[e+1], s2 = csr[e+2], s3 = csr[e+3];
          float d0 = dinv[s0], d1 = dinv[s1], d2 = dinv[s2], d3 = dinv[s3];
          float4 v0 = *(const float4*)(xc + (size_t)s0*64);
          float4 v1 = *(const float4*)(xc + (size_t)s1*64);
          float4 v2 = *(const float4*)(xc + (size_t)s2*64);
          float4 v3 = *(const float4*)(xc + (size_t)s3*64);
          ax += d0*v0.x + d1*v1.x + d2*v2.x + d3*v3.x;
          ay += d0*v0.y + d1*v1.y + d2*v2.y + d3*v3.y;
          az += d0*v0.z + d1*v1.z + d2*v2.z + d3*v3.z;
          aw += d0*v0.w + d1*v1.w + d2*v2.w + d3*v3.w;
        }
        for (; e < end; ++e){
          int s0 = csr[e];
          float d0 = dinv[s0];
          float4 v = *(const float4*)(xc + (size_t)s0*64);
          ax += d0*v.x; ay += d0*v.y; az += d0*v.z; aw += d0*v.w;
        }
        float o[4] = {dn*ax, dn*ay, dn*az, dn*aw};
        ushort4 hh, hl;
        unsigned short* hp = (unsigned short*)&hh;
        unsigned short* lp = (unsigned short*)&hl;
        #pragma unroll
        for (int j = 0; j < 4; ++j){
          unsigned short hi = f2bf(o[j]);
          hp[j] = hi; lp[j] = f2bf(o[j] - bf2f(hi));
        }
        *(ushort4*)&Xh[ln][c] = hh;
        *(ushort4*)&Xl[ln][c] = hl;
      }
    }
  }
  __syncthreads();

  const int wv = tid >> 6, lane = tid & 63, quad = lane >> 4, tcol = lane & 15;

  // phase 2a: h1 = relu(h0 @ W1 + b1) -> LDS (C-layout scatter)
  {
    f32x4 acc[8];
    #pragma unroll
    for (int t = 0; t < 8; ++t){ acc[t][0]=0.f; acc[t][1]=0.f; acc[t][2]=0.f; acc[t][3]=0.f; }
    #pragma unroll
    for (int kc = 0; kc < 2; ++kc){
      short8v a_h = *(const short8v*)&Xh[wv*16 + tcol][kc*32 + quad*8];
      short8v a_l = *(const short8v*)&Xl[wv*16 + tcol][kc*32 + quad*8];
      const unsigned short* bb = W1h + ((size_t)(kc*8)*64 + lane)*8;
      const unsigned short* bl = W1l + ((size_t)(kc*8)*64 + lane)*8;
      #pragma unroll
      for (int nt = 0; nt < 8; ++nt){
        short8v b_h = *(const short8v*)(bb + (size_t)nt*512);
        short8v b_l = *(const short8v*)(bl + (size_t)nt*512);
        acc[nt] = __builtin_amdgcn_mfma_f32_16x16x32_bf16(a_h, b_h, acc[nt], 0, 0, 0);
        acc[nt] = __builtin_amdgcn_mfma_f32_16x16x32_bf16(a_l, b_h, acc[nt], 0, 0, 0);
        acc[nt] = __builtin_amdgcn_mfma_f32_16x16x32_bf16(a_h, b_l, acc[nt], 0, 0, 0);
      }
    }
    float bv[8];
    #pragma unroll
    for (int nt = 0; nt < 8; ++nt) bv[nt] = b1[nt*16 + tcol];
    #pragma unroll
    for (int reg = 0; reg < 4; ++reg){
      int lrow = wv*16 + quad*4 + reg;
      #pragma unroll
      for (int nt = 0; nt < 8; ++nt){
        float o = fmaxf(acc[nt][reg] + bv[nt], 0.f);
        unsigned short hi = f2bf(o);
        Hh[lrow][nt*16 + tcol] = hi;
        Hl[lrow][nt*16 + tcol] = f2bf(o - bf2f(hi));
      }
    }
  }
  __syncthreads();

  // phase 2b: p = dinv * (h1 @ W2_0) -> global
  {
    f32x4 acc[8];
    #pragma unroll
    for (int t = 0; t < 8; ++t){ acc[t][0]=0.f; acc[t][1]=0.f; acc[t][2]=0.f; acc[t][3]=0.f; }
    #pragma unroll
    for (int kc = 0; kc < 4; ++kc){
      short8v a_h = *(const short8v*)&Hh[wv*16 + tcol][kc*32 + quad*8];
      short8v a_l = *(const short8v*)&Hl[wv*16 + tcol][kc*32 + quad*8];
      const unsigned short* bb = W2h0 + ((size_t)(kc*8)*64 + lane)*8;
      const unsigned short* bl = W2l0 + ((size_t)(kc*8)*64 + lane)*8;
      #pragma unroll
      for (int nt = 0; nt < 8; ++nt){
        short8v b_h = *(const short8v*)(bb + (size_t)nt*512);
        short8v b_l = *(const short8v*)(bl + (size_t)nt*512);
        acc[nt] = __builtin_amdgcn_mfma_f32_16x16x32_bf16(a_h, b_h, acc[nt], 0, 0, 0);
        acc[nt] = __builtin_amdgcn_mfma_f32_16x16x32_bf16(a_l, b_h, acc[nt], 0, 0, 0);
        acc[nt] = __builtin_amdgcn_mfma_f32_16x16x32_bf16(a_h, b_l, acc[nt], 0, 0, 0);
      }
    }
    #pragma unroll
    for (int reg = 0; reg < 4; ++reg){
      int grow = node0 + wv*16 + quad*4 + reg;
      if (grow < N){
        float sc = dinv[grow];
        float* op = pout + (size_t)grow*128 + tcol;
        #pragma unroll
        for (int nt = 0; nt < 8; ++nt) op[nt*16] = acc[nt][reg] * sc;
      }
    }
  }
}

// ---------------- fused mid layer: gather(p)+bias+relu -> GEMM(W2_i)*dinv -> pout ----------------
__global__ __launch_bounds__(256) void k_fuse(const float* __restrict__ p, const int* __restrict__ rowptr,
                                              const int* __restrict__ csr, const float* __restrict__ dinv,
                                              const float* __restrict__ bias,
                                              const unsigned short* __restrict__ Bh, const unsigned short* __restrict__ Bl,
                                              float* __restrict__ pout, int N){
  __shared__ unsigned short Hh[64][168], Hl[64][168];   // 43 KB total -> 3 blocks/CU (grid 1563 = 2x768+27)
  const int tid = threadIdx.x;
  const int node0 = blockIdx.x*64;

  // phase 1: gather (32 lanes/node, 8 iters of 8 nodes) + relu(dinv*sum + bias) -> split into LDS
  {
    const int nl = tid >> 5;
    const int c  = (tid & 31) * 4;
    const float* pc = p + c;
    for (int it = 0; it < 8; ++it){
      int ln = it*8 + nl;
      int node = node0 + ln;
      if (node < N){
        int e = rowptr[node], end = rowptr[node+1];
        float4 s = *(const float4*)(p + (size_t)node*128 + c);
        float ax = s.x, ay = s.y, az = s.z, aw = s.w;
        for (; e + 4 <= end; e += 4){
          int s0 = csr[e], s1 = csr[e+1], s2 = csr[e+2], s3 = csr[e+3];
          float4 v0 = *(const float4*)(pc + (size_t)s0*128);
          float4 v1 = *(const float4*)(pc + (size_t)s1*128);
          float4 v2 = *(const float4*)(pc + (size_t)s2*128);
          float4 v3 = *(const float4*)(pc + (size_t)s3*128);
          ax += v0.x+v1.x+v2.x+v3.x; ay += v0.y+v1.y+v2.y+v3.y;
          az += v0.z+v1.z+v2.z+v3.z; aw += v0.w+v1.w+v2.w+v3.w;
        }
        for (; e < end; ++e){
          float4 v = *(const float4*)(pc + (size_t)csr[e]*128);
          ax += v.x; ay += v.y; az += v.z; aw += v.w;
        }
        float d = dinv[node];
        float o[4] = {fmaxf(d*ax + bias[c],   0.f), fmaxf(d*ay + bias[c+1], 0.f),
                      fmaxf(d*az + bias[c+2], 0.f), fmaxf(d*aw + bias[c+3], 0.f)};
        ushort4 hh, hl;
        unsigned short* hp = (unsigned short*)&hh;
        unsigned short* lp = (unsigned short*)&hl;
        #pragma unroll
        for (int j = 0; j < 4; ++j){
          unsigned short hi = f2bf(o[j]);
          hp[j] = hi; lp[j] = f2bf(o[j] - bf2f(hi));
        }
        *(ushort4*)&Hh[ln][c] = hh;
        *(ushort4*)&Hl[ln][c] = hl;
      }
    }
  }
  __syncthreads();

  // phase 2: p' = dinv * (h @ W2_i)
  const int wv = tid >> 6, lane = tid & 63, quad = lane >> 4, tcol = lane & 15;
  f32x4 acc[8];
  #pragma unroll
  for (int t = 0; t < 8; ++t){ acc[t][0]=0.f; acc[t][1]=0.f; acc[t][2]=0.f; acc[t][3]=0.f; }
  #pragma unroll
  for (int kc = 0; kc < 4; ++kc){
    short8v a_h = *(const short8v*)&Hh[wv*16 + tcol][kc*32 + quad*8];
    short8v a_l = *(const short8v*)&Hl[wv*16 + tcol][kc*32 + quad*8];
    const unsigned short* bb = Bh + ((size_t)(kc*8)*64 + lane)*8;
    const unsigned short* bl = Bl + ((size_t)(kc*8)*64 + lane)*8;
    #pragma unroll
    for (int nt = 0; nt < 8; ++nt){
      short8v b_h = *(const short8v*)(bb + (size_t)nt*512);
      short8v b_l = *(const short8v*)(bl + (size_t)nt*512);
      acc[nt] = __builtin_amdgcn_mfma_f32_16x16x32_bf16(a_h, b_h, acc[nt], 0, 0, 0);
      acc[nt] = __builtin_amdgcn_mfma_f32_16x16x32_bf16(a_l, b_h, acc[nt], 0, 0, 0);
      acc[nt] = __builtin_amdgcn_mfma_f32_16x16x32_bf16(a_h, b_l, acc[nt], 0, 0, 0);
    }
  }
  #pragma unroll
  for (int reg = 0; reg < 4; ++reg){
    int grow = node0 + wv*16 + quad*4 + reg;
    if (grow < N){
      float sc = dinv[grow];
      float* op = pout + (size_t)grow*128 + tcol;
      #pragma unroll
      for (int nt = 0; nt < 8; ++nt) op[nt*16] = acc[nt][reg] * sc;
    }
  }
}

// ---------------- last 128-wide agg fused with W3 projection (32 lanes/node) ----------------
__global__ __launch_bounds__(256) void k_agg_last(const float* __restrict__ p, const int* __restrict__ rowptr,
                                                  const int* __restrict__ csr, const float* __restrict__ dinv,
                                                  const float* __restrict__ bias, const float* __restrict__ W3,
                                                  float* __restrict__ p5, int N){
  const int tid = threadIdx.x;
  const int node = blockIdx.x*8 + (tid >> 5);
  if (node >= N) return;
  const int c = (tid & 31) * 4;
  const float* pc = p + c;
  int e = rowptr[node], end = rowptr[node+1];
  float4 s = *(const float4*)(p + (size_t)node*128 + c);
  float ax = s.x, ay = s.y, az = s.z, aw = s.w;
  for (; e + 4 <= end; e += 4){
    int s0 = csr[e], s1 = csr[e+1], s2 = csr[e+2], s3 = csr[e+3];
    float4 v0 = *(const float4*)(pc + (size_t)s0*128);
    float4 v1 = *(const float4*)(pc + (size_t)s1*128);
    float4 v2 = *(const float4*)(pc + (size_t)s2*128);
    float4 v3 = *(const float4*)(pc + (size_t)s3*128);
    ax += v0.x+v1.x+v2.x+v3.x; ay += v0.y+v1.y+v2.y+v3.y;
    az += v0.z+v1.z+v2.z+v3.z; aw += v0.w+v1.w+v2.w+v3.w;
  }
  for (; e < end; ++e){
    float4 v = *(const float4*)(pc + (size_t)csr[e]*128);
    ax += v.x; ay += v.y; az += v.z; aw += v.w;
  }
  float d = dinv[node];
  float o0 = fmaxf(d*ax + bias[c],   0.f);
  float o1 = fmaxf(d*ay + bias[c+1], 0.f);
  float o2 = fmaxf(d*az + bias[c+2], 0.f);
  float o3 = fmaxf(d*aw + bias[c+3], 0.f);
  float4 w = *(const float4*)(W3 + c);
  float sdot = o0*w.x + o1*w.y + o2*w.z + o3*w.w;
  #pragma unroll
  for (int m = 16; m >= 1; m >>= 1) sdot += __shfl_xor(sdot, m, 32);
  if ((tid & 31) == 0) p5[node] = d * sdot;
}

// ---------------- final scalar aggregation ----------------
__global__ __launch_bounds__(256) void k_agg1(const float* __restrict__ p5, const int* __restrict__ rowptr,
                                              const int* __restrict__ csr, const float* __restrict__ dinv,
                                              const float* __restrict__ b3, float* __restrict__ out, int N){
  int n = blockIdx.x*256 + threadIdx.x;
  if (n >= N) return;
  int e = rowptr[n], end = rowptr[n+1];
  float acc = p5[n];
  for (; e + 4 <= end; e += 4)
    acc += p5[csr[e]] + p5[csr[e+1]] + p5[csr[e+2]] + p5[csr[e+3]];
  for (; e < end; ++e) acc += p5[csr[e]];
  out[n] = dinv[n]*acc + b3[0];
}

extern "C" void kernel_launch(void* const* d_in, const int* in_sizes, int n_in,
                              void* d_out, int out_size, void* d_ws, size_t ws_size,
                              hipStream_t stream){
  const float* x  = (const float*)d_in[0];
  const int*   ei = (const int*)  d_in[1];
  const float* W1 = (const float*)d_in[2];
  const float* b1 = (const float*)d_in[3];
  const float* W2 = (const float*)d_in[4];
  const float* b2 = (const float*)d_in[5];
  const float* W3 = (const float*)d_in[6];
  const float* b3 = (const float*)d_in[7];
  float* out = (float*)d_out;

  const int N = in_sizes[0] / 64;
  const int E = in_sizes[1] / 2;
  const int L = in_sizes[4] / (128*128);
  const int* src = ei;
  const int* dst = ei + E;

  char* ws = (char*)d_ws;
  size_t off = 0;
  auto alloc = [&](size_t bytes){ void* p = ws + off; off += (bytes + 255) & ~(size_t)255; return p; };
  int*   counts = (int*)  alloc((size_t)N*4);
  int*   rowptr = (int*)  alloc((size_t)(N+1)*4);
  int*   bsum   = (int*)  alloc(128*4);
  int*   boff   = (int*)  alloc(128*4);
  float* dinv   = (float*)alloc((size_t)N*4);
  float* p5     = (float*)alloc((size_t)N*4);
  int*   rank   = (int*)  alloc((size_t)E*4);
  int*   csr    = (int*)  alloc((size_t)E*4);
  float* pA     = (float*)alloc((size_t)N*128*4);
  float* pB     = (float*)alloc((size_t)N*128*4);
  unsigned short* W1h = (unsigned short*)alloc(64*128*2);
  unsigned short* W1l = (unsigned short*)alloc(64*128*2);
  unsigned short* W2h = (unsigned short*)alloc((size_t)L*128*128*2);
  unsigned short* W2l = (unsigned short*)alloc((size_t)L*128*128*2);
  (void)ws_size; (void)n_in; (void)out_size;

  hipMemsetAsync(counts, 0, (size_t)N*4, stream);

  k_count<<<DIV_UP(E,256),256,0,stream>>>(dst, counts, rank, E);
  int nb = DIV_UP(N,1024);
  k_scan1<<<nb,1024,0,stream>>>(counts, rowptr, bsum, dinv, N);
  k_scan2<<<1,128,0,stream>>>(bsum, boff, nb, rowptr, N);
  k_scan3<<<nb,1024,0,stream>>>(rowptr, boff, N);
  k_fill_g<<<1024,256,0,stream>>>(src, dst, rank, rowptr, csr, E, N);

  int wtot = 64*128 + L*128*128;
  k_split_w<<<DIV_UP(wtot,256),256,0,stream>>>(W1, W2, W1h, W1l, W2h, W2l, L);

  // fused layer chain
  k_fuse1<<<DIV_UP(N,64),256,0,stream>>>(x, rowptr, csr, dinv, W1h, W1l, b1,
                                         W2h, W2l, pA, N);
  float* pin = pA; float* pout = pB;
  for (int i = 1; i < L; ++i){
    k_fuse<<<DIV_UP(N,64),256,0,stream>>>(pin, rowptr, csr, dinv, b2 + (size_t)(i-1)*128,
                                          W2h + (size_t)i*128*128, W2l + (size_t)i*128*128, pout, N);
    float* t = pin; pin = pout; pout = t;
  }
  k_agg_last<<<DIV_UP(N,8),256,0,stream>>>(pin, rowptr, csr, dinv, b2 + (size_t)(L-1)*128, W3, p5, N);

  k_agg1<<<DIV_UP(N,256),256,0,stream>>>(p5, rowptr, csr, dinv, b3, out, N);
}

// Round 9
// 763.897 us; speedup vs baseline: 1.0080x; 1.0080x over previous
//
#include <hip/hip_runtime.h>
#include <hip/hip_bf16.h>

#define DIV_UP(a,b) (((a)+(b)-1)/(b))

typedef __attribute__((ext_vector_type(8))) short short8v;
typedef __attribute__((ext_vector_type(4))) float f32x4;

__device__ inline unsigned short f2bf(float f){
  unsigned u = __float_as_uint(f);
  u += 0x7FFFu + ((u >> 16) & 1u);          // RNE
  return (unsigned short)(u >> 16);
}
__device__ inline float bf2f(unsigned short h){ return __uint_as_float(((unsigned)h) << 16); }

// ---------------- preprocessing: degree, dinv, CSR-by-dst (XCD-grouped, R7-proven) ----------------

__global__ __launch_bounds__(256) void k_count_g(const int* __restrict__ dst, int* __restrict__ counts,
                                                 int E, int N){
  const int g   = blockIdx.x & 7;
  const int bi  = blockIdx.x >> 3;
  const int bpg = gridDim.x >> 3;
  const int chunk = (N + 7) >> 3;
  const int lo = g*chunk;
  const int hi = min(lo + chunk, N);
  for (int e = bi*256 + threadIdx.x; e < E; e += bpg*256){
    int d = dst[e];
    if (d >= lo && d < hi) atomicAdd(&counts[d], 1);
  }
}

__global__ __launch_bounds__(256) void k_fill_g(const int* __restrict__ src, const int* __restrict__ dst,
                                                const int* __restrict__ rowptr, int* __restrict__ fill,
                                                int* __restrict__ csr, int E, int N){
  const int g   = blockIdx.x & 7;
  const int bi  = blockIdx.x >> 3;
  const int bpg = gridDim.x >> 3;
  const int chunk = (N + 7) >> 3;
  const int lo = g*chunk;
  const int hi = min(lo + chunk, N);
  for (int e = bi*256 + threadIdx.x; e < E; e += bpg*256){
    int d = dst[e];
    if (d >= lo && d < hi){
      int pos = rowptr[d] + atomicAdd(&fill[d], 1);
      csr[pos] = src[e];
    }
  }
}

__global__ __launch_bounds__(1024) void k_scan1(const int* __restrict__ counts, int* __restrict__ rowptr,
                                                int* __restrict__ bsum, float* __restrict__ dinv, int N){
  __shared__ int s[1024];
  int t = threadIdx.x, g = blockIdx.x*1024 + t;
  int v = (g < N) ? counts[g] : 0;
  if (g < N) dinv[g] = rsqrtf((float)(v + 1));   // +1 = self-loop
  s[t] = v; __syncthreads();
  for (int off = 1; off < 1024; off <<= 1){
    int u = (t >= off) ? s[t-off] : 0; __syncthreads();
    s[t] += u; __syncthreads();
  }
  if (g < N) rowptr[g] = s[t] - v;
  if (t == 1023) bsum[blockIdx.x] = s[1023];
}

__global__ __launch_bounds__(128) void k_scan2(const int* __restrict__ bsum, int* __restrict__ boff,
                                               int nb, int* __restrict__ rowptr, int N){
  __shared__ int s[128];
  int t = threadIdx.x;
  int v = (t < nb) ? bsum[t] : 0;
  s[t] = v; __syncthreads();
  for (int off = 1; off < 128; off <<= 1){
    int u = (t >= off) ? s[t-off] : 0; __syncthreads();
    s[t] += u; __syncthreads();
  }
  if (t < nb) boff[t] = s[t] - v;
  if (t == 127) rowptr[N] = s[127];
}

__global__ __launch_bounds__(1024) void k_scan3(int* __restrict__ rowptr, const int* __restrict__ boff, int N){
  int g = blockIdx.x*1024 + threadIdx.x;
  if (g < N) rowptr[g] += boff[blockIdx.x];
}

// ---------------- split weights into FRAGMENT-LINEARIZED bf16 hi/lo ----------------
__global__ __launch_bounds__(256) void k_split_w(const float* __restrict__ W1, const float* __restrict__ W2,
                                                 unsigned short* __restrict__ W1h, unsigned short* __restrict__ W1l,
                                                 unsigned short* __restrict__ W2h, unsigned short* __restrict__ W2l,
                                                 int L){
  int idx = blockIdx.x*256 + threadIdx.x;
  int n1 = 64*128;
  if (idx < n1){
    int j = idx & 7, lane = (idx >> 3) & 63, t = idx >> 9;   // t = kc*8+nt, kc<2 (K=64)
    int kc = t >> 3, nt = t & 7;
    int tcol = lane & 15, quad = lane >> 4;
    int k = kc*32 + quad*8 + j, n = nt*16 + tcol;
    float v = W1[k*128 + n];
    unsigned short hi = f2bf(v);
    W1h[idx] = hi; W1l[idx] = f2bf(v - bf2f(hi));
  } else {
    int idx2 = idx - n1;
    if (idx2 >= L*128*128) return;
    int i = idx2 >> 14, r = idx2 & 16383;
    int j = r & 7, lane = (r >> 3) & 63, t = r >> 9;         // t = kc*8+nt, kc<4 (K=128)
    int kc = t >> 3, nt = t & 7;
    int tcol = lane & 15, quad = lane >> 4;
    int k = kc*32 + quad*8 + j, n = nt*16 + tcol;
    float v = W2[(size_t)i*16384 + k*128 + n];
    unsigned short hi = f2bf(v);
    W2h[idx2] = hi; W2l[idx2] = f2bf(v - bf2f(hi));
  }
}

// ---------------- fused 64-wide aggregation of raw x -> split bf16 output ----------------
__global__ __launch_bounds__(256) void k_agg64x(const float* __restrict__ x, const int* __restrict__ rowptr,
                                                const int* __restrict__ csr, const float* __restrict__ dinv,
                                                unsigned short* __restrict__ oh, unsigned short* __restrict__ ol,
                                                int N){
  const int tid = threadIdx.x;
  const int node = blockIdx.x*16 + (tid >> 4);
  if (node >= N) return;
  const int c = (tid & 15) * 4;
  const float* xc = x + c;
  const float dn = dinv[node];
  float4 s = *(const float4*)(x + (size_t)node*64 + c);
  float ax = dn*s.x, ay = dn*s.y, az = dn*s.z, aw = dn*s.w;
  int e = rowptr[node], end = rowptr[node+1];
  for (; e + 4 <= end; e += 4){
    int s0 = csr[e], s1 = csr[e+1], s2 = csr[e+2], s3 = csr[e+3];
    float d0 = dinv[s0], d1 = dinv[s1], d2 = dinv[s2], d3 = dinv[s3];
    float4 v0 = *(const float4*)(xc + (size_t)s0*64);
    float4 v1 = *(const float4*)(xc + (size_t)s1*64);
    float4 v2 = *(const float4*)(xc + (size_t)s2*64);
    float4 v3 = *(const float4*)(xc + (size_t)s3*64);
    ax += d0*v0.x + d1*v1.x + d2*v2.x + d3*v3.x;
    ay += d0*v0.y + d1*v1.y + d2*v2.y + d3*v3.y;
    az += d0*v0.z + d1*v1.z + d2*v2.z + d3*v3.z;
    aw += d0*v0.w + d1*v1.w + d2*v2.w + d3*v3.w;
  }
  for (; e < end; ++e){
    int s0 = csr[e];
    float d0 = dinv[s0];
    float4 v = *(const float4*)(xc + (size_t)s0*64);
    ax += d0*v.x; ay += d0*v.y; az += d0*v.z; aw += d0*v.w;
  }
  float o[4] = {dn*ax, dn*ay, dn*az, dn*aw};
  ushort4 hh, hl;
  unsigned short* hp = (unsigned short*)&hh;
  unsigned short* lp = (unsigned short*)&hl;
  #pragma unroll
  for (int j = 0; j < 4; ++j){
    unsigned short hi = f2bf(o[j]);
    hp[j] = hi; lp[j] = f2bf(o[j] - bf2f(hi));
  }
  *(ushort4*)(oh + (size_t)node*64 + c) = hh;
  *(ushort4*)(ol + (size_t)node*64 + c) = hl;
}

// ---------------- MFMA GEMM v2: LDS-staged A + LDS-transposed epilogue ----------------
// Block: 64 rows x 128 cols, 256 thr = 4 waves (wave wv owns rows wv*16..+15, all 128 cols).
// A staged coalesced -> LDS (stride K+8 shorts). Epilogue: acc -> 64x132 fp32 LDS tile (2-way banks)
// -> linear re-read -> contiguous 1KB/wave global stores. Same arithmetic as v1 (bit-identical).
template<int K, int EPI>
__global__ __launch_bounds__(256) void k_gemm_m2(const unsigned short* __restrict__ Ah,
                                                 const unsigned short* __restrict__ Al,
                                                 const unsigned short* __restrict__ Bh,
                                                 const unsigned short* __restrict__ Bl,
                                                 const float* __restrict__ bias, const float* __restrict__ dinv,
                                                 float* __restrict__ outF,
                                                 unsigned short* __restrict__ outH, unsigned short* __restrict__ outL,
                                                 int N){
  constexpr int AS = K + 8;                       // LDS stride (shorts)
  constexpr int ABYTES = 64*AS*2*2;               // Ah+Al staging
  constexpr int CBYTES = 64*132*4;                // epilogue fp32 tile
  constexpr int SBYTES = (ABYTES > CBYTES) ? ABYTES : CBYTES;
  __shared__ __align__(16) char smem[SBYTES];
  unsigned short (*AhS)[AS] = (unsigned short(*)[AS])smem;
  unsigned short (*AlS)[AS] = (unsigned short(*)[AS])(smem + 64*AS*2);
  float (*CS)[132] = (float(*)[132])smem;

  const int tid  = threadIdx.x;
  const int wv   = tid >> 6;
  const int lane = tid & 63;
  const int quad = lane >> 4;
  const int tcol = lane & 15;
  const int row0 = blockIdx.x*64;

  // ---- stage A (hi+lo) coalesced ----
  #pragma unroll
  for (int it = 0; it < K/32; ++it){
    int idx = it*2048 + tid*8;                    // short index in 64xK tile
    int row = idx / K, col = idx % K;
    int grow = row0 + row; if (grow >= N) grow = N - 1;
    *(short8v*)&AhS[row][col] = *(const short8v*)(Ah + (size_t)grow*K + col);
    *(short8v*)&AlS[row][col] = *(const short8v*)(Al + (size_t)grow*K + col);
  }
  __syncthreads();

  // ---- MFMA main loop ----
  f32x4 acc[8];
  #pragma unroll
  for (int t = 0; t < 8; ++t){ acc[t][0]=0.f; acc[t][1]=0.f; acc[t][2]=0.f; acc[t][3]=0.f; }
  #pragma unroll
  for (int kc = 0; kc < K/32; ++kc){
    short8v a_h = *(const short8v*)&AhS[wv*16 + tcol][kc*32 + quad*8];
    short8v a_l = *(const short8v*)&AlS[wv*16 + tcol][kc*32 + quad*8];
    const unsigned short* bb = Bh + ((size_t)(kc*8)*64 + lane)*8;
    const unsigned short* bl = Bl + ((size_t)(kc*8)*64 + lane)*8;
    #pragma unroll
    for (int nt = 0; nt < 8; ++nt){
      short8v b_h = *(const short8v*)(bb + (size_t)nt*512);
      short8v b_l = *(const short8v*)(bl + (size_t)nt*512);
      acc[nt] = __builtin_amdgcn_mfma_f32_16x16x32_bf16(a_h, b_h, acc[nt], 0, 0, 0);
      acc[nt] = __builtin_amdgcn_mfma_f32_16x16x32_bf16(a_l, b_h, acc[nt], 0, 0, 0);
      acc[nt] = __builtin_amdgcn_mfma_f32_16x16x32_bf16(a_h, b_l, acc[nt], 0, 0, 0);
    }
  }
  __syncthreads();                                // all A reads done -> safe to overwrite smem

  // ---- epilogue: C-layout scatter into LDS (2-way banks, free) ----
  #pragma unroll
  for (int reg = 0; reg < 4; ++reg){
    int lrow = wv*16 + quad*4 + reg;
    #pragma unroll
    for (int nt = 0; nt < 8; ++nt)
      CS[lrow][nt*16 + tcol] = acc[nt][reg];
  }
  __syncthreads();

  // ---- linear re-read -> coalesced global stores (1KB/wave/instr) ----
  #pragma unroll
  for (int it = 0; it < 8; ++it){
    int lidx = it*1024 + tid*4;                   // float index in 64x128 tile
    int row = lidx >> 7, col = lidx & 127;
    int grow = row0 + row;
    if (grow < N){
      float4 v = *(const float4*)&CS[row][col];
      if (EPI == 0){
        float sc = dinv[grow];
        v.x *= sc; v.y *= sc; v.z *= sc; v.w *= sc;
        *(float4*)(outF + (size_t)grow*128 + col) = v;
      } else {
        float4 b = *(const float4*)(bias + col);
        float o[4] = {fmaxf(v.x + b.x, 0.f), fmaxf(v.y + b.y, 0.f),
                      fmaxf(v.z + b.z, 0.f), fmaxf(v.w + b.w, 0.f)};
        ushort4 hh, hl;
        unsigned short* hp = (unsigned short*)&hh;
        unsigned short* lp = (unsigned short*)&hl;
        #pragma unroll
        for (int j = 0; j < 4; ++j){
          unsigned short hi = f2bf(o[j]);
          hp[j] = hi; lp[j] = f2bf(o[j] - bf2f(hi));
        }
        *(ushort4*)(outH + (size_t)grow*128 + col) = hh;
        *(ushort4*)(outL + (size_t)grow*128 + col) = hl;
      }
    }
  }
}

// ---------------- 128-wide CSR aggregation (32 lanes/node) -> split bf16 output ----------------
__global__ __launch_bounds__(256) void k_agg128(const float* __restrict__ p, const int* __restrict__ rowptr,
                                                const int* __restrict__ csr, const float* __restrict__ dinv,
                                                const float* __restrict__ bias,
                                                unsigned short* __restrict__ oh, unsigned short* __restrict__ ol,
                                                int N){
  const int tid = threadIdx.x;
  const int node = blockIdx.x*8 + (tid >> 5);
  if (node >= N) return;
  const int c = (tid & 31) * 4;
  const float* pc = p + c;
  int e = rowptr[node], end = rowptr[node+1];
  float4 s = *(const float4*)(p + (size_t)node*128 + c);
  float ax = s.x, ay = s.y, az = s.z, aw = s.w;
  for (; e + 4 <= end; e += 4){
    int s0 = csr[e], s1 = csr[e+1], s2 = csr[e+2], s3 = csr[e+3];
    float4 v0 = *(const float4*)(pc + (size_t)s0*128);
    float4 v1 = *(const float4*)(pc + (size_t)s1*128);
    float4 v2 = *(const float4*)(pc + (size_t)s2*128);
    float4 v3 = *(const float4*)(pc + (size_t)s3*128);
    ax += v0.x+v1.x+v2.x+v3.x; ay += v0.y+v1.y+v2.y+v3.y;
    az += v0.z+v1.z+v2.z+v3.z; aw += v0.w+v1.w+v2.w+v3.w;
  }
  for (; e < end; ++e){
    float4 v = *(const float4*)(pc + (size_t)csr[e]*128);
    ax += v.x; ay += v.y; az += v.z; aw += v.w;
  }
  float d = dinv[node];
  float o[4] = {fmaxf(d*ax + bias[c],   0.f), fmaxf(d*ay + bias[c+1], 0.f),
                fmaxf(d*az + bias[c+2], 0.f), fmaxf(d*aw + bias[c+3], 0.f)};
  ushort4 hh, hl;
  unsigned short* hp = (unsigned short*)&hh;
  unsigned short* lp = (unsigned short*)&hl;
  #pragma unroll
  for (int j = 0; j < 4; ++j){
    unsigned short hi = f2bf(o[j]);
    hp[j] = hi; lp[j] = f2bf(o[j] - bf2f(hi));
  }
  *(ushort4*)(oh + (size_t)node*128 + c) = hh;
  *(ushort4*)(ol + (size_t)node*128 + c) = hl;
}

// ---------------- last 128-wide agg fused with W3 projection (32 lanes/node) ----------------
__global__ __launch_bounds__(256) void k_agg_last(const float* __restrict__ p, const int* __restrict__ rowptr,
                                                  const int* __restrict__ csr, const float* __restrict__ dinv,
                                                  const float* __restrict__ bias, const float* __restrict__ W3,
                                                  float* __restrict__ p5, int N){
  const int tid = threadIdx.x;
  const int node = blockIdx.x*8 + (tid >> 5);
  if (node >= N) return;
  const int c = (tid & 31) * 4;
  const float* pc = p + c;
  int e = rowptr[node], end = rowptr[node+1];
  float4 s = *(const float4*)(p + (size_t)node*128 + c);
  float ax = s.x, ay = s.y, az = s.z, aw = s.w;
  for (; e + 4 <= end; e += 4){
    int s0 = csr[e], s1 = csr[e+1], s2 = csr[e+2], s3 = csr[e+3];
    float4 v0 = *(const float4*)(pc + (size_t)s0*128);
    float4 v1 = *(const float4*)(pc + (size_t)s1*128);
    float4 v2 = *(const float4*)(pc + (size_t)s2*128);
    float4 v3 = *(const float4*)(pc + (size_t)s3*128);
    ax += v0.x+v1.x+v2.x+v3.x; ay += v0.y+v1.y+v2.y+v3.y;
    az += v0.z+v1.z+v2.z+v3.z; aw += v0.w+v1.w+v2.w+v3.w;
  }
  for (; e < end; ++e){
    float4 v = *(const float4*)(pc + (size_t)csr[e]*128);
    ax += v.x; ay += v.y; az += v.z; aw += v.w;
  }
  float d = dinv[node];
  float o0 = fmaxf(d*ax + bias[c],   0.f);
  float o1 = fmaxf(d*ay + bias[c+1], 0.f);
  float o2 = fmaxf(d*az + bias[c+2], 0.f);
  float o3 = fmaxf(d*aw + bias[c+3], 0.f);
  float4 w = *(const float4*)(W3 + c);
  float sdot = o0*w.x + o1*w.y + o2*w.z + o3*w.w;
  #pragma unroll
  for (int m = 16; m >= 1; m >>= 1) sdot += __shfl_xor(sdot, m, 32);
  if ((tid & 31) == 0) p5[node] = d * sdot;
}

// ---------------- final scalar aggregation ----------------
__global__ __launch_bounds__(256) void k_agg1(const float* __restrict__ p5, const int* __restrict__ rowptr,
                                              const int* __restrict__ csr, const float* __restrict__ dinv,
                                              const float* __restrict__ b3, float* __restrict__ out, int N){
  int n = blockIdx.x*256 + threadIdx.x;
  if (n >= N) return;
  int e = rowptr[n], end = rowptr[n+1];
  float acc = p5[n];
  for (; e + 4 <= end; e += 4)
    acc += p5[csr[e]] + p5[csr[e+1]] + p5[csr[e+2]] + p5[csr[e+3]];
  for (; e < end; ++e) acc += p5[csr[e]];
  out[n] = dinv[n]*acc + b3[0];
}

extern "C" void kernel_launch(void* const* d_in, const int* in_sizes, int n_in,
                              void* d_out, int out_size, void* d_ws, size_t ws_size,
                              hipStream_t stream){
  const float* x  = (const float*)d_in[0];
  const int*   ei = (const int*)  d_in[1];
  const float* W1 = (const float*)d_in[2];
  const float* b1 = (const float*)d_in[3];
  const float* W2 = (const float*)d_in[4];
  const float* b2 = (const float*)d_in[5];
  const float* W3 = (const float*)d_in[6];
  const float* b3 = (const float*)d_in[7];
  float* out = (float*)d_out;

  const int N = in_sizes[0] / 64;
  const int E = in_sizes[1] / 2;
  const int L = in_sizes[4] / (128*128);
  const int* src = ei;
  const int* dst = ei + E;

  char* ws = (char*)d_ws;
  size_t off = 0;
  auto alloc = [&](size_t bytes){ void* p = ws + off; off += (bytes + 255) & ~(size_t)255; return p; };
  size_t cntb = ((size_t)N*4 + 255) & ~(size_t)255;
  int*   counts = (int*)  alloc(cntb*2);       // counts + fillc adjacent -> one memset
  int*   fillc  = (int*)((char*)counts + cntb);
  int*   rowptr = (int*)  alloc((size_t)(N+1)*4);
  int*   bsum   = (int*)  alloc(128*4);
  int*   boff   = (int*)  alloc(128*4);
  float* dinv   = (float*)alloc((size_t)N*4);
  float* p5     = (float*)alloc((size_t)N*4);
  int*   csr    = (int*)  alloc((size_t)E*4);
  float* pF     = (float*)alloc((size_t)N*128*4);          // fp32 GEMM output (gather target)
  unsigned short* hh = (unsigned short*)alloc((size_t)N*128*2);
  unsigned short* hl = (unsigned short*)alloc((size_t)N*128*2);
  unsigned short* W1h = (unsigned short*)alloc(64*128*2);
  unsigned short* W1l = (unsigned short*)alloc(64*128*2);
  unsigned short* W2h = (unsigned short*)alloc((size_t)L*128*128*2);
  unsigned short* W2l = (unsigned short*)alloc((size_t)L*128*128*2);
  // 64-wide split buffers alias pF (consumed before pF is first written)
  unsigned short* hh0 = (unsigned short*)pF;
  unsigned short* hl0 = ((unsigned short*)pF) + (size_t)N*64;
  (void)ws_size; (void)n_in; (void)out_size;

  hipMemsetAsync(counts, 0, cntb*2, stream);

  k_count_g<<<1024,256,0,stream>>>(dst, counts, E, N);
  int nb = DIV_UP(N,1024);
  k_scan1<<<nb,1024,0,stream>>>(counts, rowptr, bsum, dinv, N);
  k_scan2<<<1,128,0,stream>>>(bsum, boff, nb, rowptr, N);
  k_scan3<<<nb,1024,0,stream>>>(rowptr, boff, N);
  k_fill_g<<<1024,256,0,stream>>>(src, dst, rowptr, fillc, csr, E, N);

  int wtot = 64*128 + L*128*128;
  k_split_w<<<DIV_UP(wtot,256),256,0,stream>>>(W1, W2, W1h, W1l, W2h, W2l, L);

  // layer 1: aggregate raw x (split-bf16 out), MFMA GEMM 64->128 (+bias+relu, split-bf16 out)
  k_agg64x<<<DIV_UP(N,16),256,0,stream>>>(x, rowptr, csr, dinv, hh0, hl0, N);
  k_gemm_m2<64,1><<<DIV_UP(N,64),256,0,stream>>>(hh0, hl0, W1h, W1l, b1, nullptr,
                                                 nullptr, hh, hl, N);

  // layers 2..4: MFMA GEMM (p = dinv*(h@W), fp32 out), then gather-agg (split-bf16 out / W3 fuse)
  for (int i = 0; i < L; ++i){
    k_gemm_m2<128,0><<<DIV_UP(N,64),256,0,stream>>>(hh, hl, W2h + (size_t)i*128*128, W2l + (size_t)i*128*128,
                                                    nullptr, dinv, pF, nullptr, nullptr, N);
    if (i < L-1)
      k_agg128<<<DIV_UP(N,8),256,0,stream>>>(pF, rowptr, csr, dinv, b2 + (size_t)i*128, hh, hl, N);
    else
      k_agg_last<<<DIV_UP(N,8),256,0,stream>>>(pF, rowptr, csr, dinv, b2 + (size_t)i*128, W3, p5, N);
  }

  // output layer: scalar gather of p5
  k_agg1<<<DIV_UP(N,256),256,0,stream>>>(p5, rowptr, csr, dinv, b3, out, N);
}

// Round 10
// 696.326 us; speedup vs baseline: 1.1058x; 1.0970x over previous
//
#include <hip/hip_runtime.h>
#include <hip/hip_bf16.h>

#define DIV_UP(a,b) (((a)+(b)-1)/(b))

typedef __attribute__((ext_vector_type(8))) short short8v;
typedef __attribute__((ext_vector_type(4))) float f32x4;

__device__ inline unsigned short f2bf(float f){
  unsigned u = __float_as_uint(f);
  u += 0x7FFFu + ((u >> 16) & 1u);          // RNE
  return (unsigned short)(u >> 16);
}
__device__ inline float bf2f(unsigned short h){ return __uint_as_float(((unsigned)h) << 16); }

// ---------------- preprocessing: degree, dinv, CSR-by-dst (XCD-grouped, R7-proven) ----------------

__global__ __launch_bounds__(256) void k_count_g(const int* __restrict__ dst, int* __restrict__ counts,
                                                 int E, int N){
  const int g   = blockIdx.x & 7;
  const int bi  = blockIdx.x >> 3;
  const int bpg = gridDim.x >> 3;
  const int chunk = (N + 7) >> 3;
  const int lo = g*chunk;
  const int hi = min(lo + chunk, N);
  for (int e = bi*256 + threadIdx.x; e < E; e += bpg*256){
    int d = dst[e];
    if (d >= lo && d < hi) atomicAdd(&counts[d], 1);
  }
}

__global__ __launch_bounds__(256) void k_fill_g(const int* __restrict__ src, const int* __restrict__ dst,
                                                const int* __restrict__ rowptr, int* __restrict__ fill,
                                                int* __restrict__ csr, int E, int N){
  const int g   = blockIdx.x & 7;
  const int bi  = blockIdx.x >> 3;
  const int bpg = gridDim.x >> 3;
  const int chunk = (N + 7) >> 3;
  const int lo = g*chunk;
  const int hi = min(lo + chunk, N);
  for (int e = bi*256 + threadIdx.x; e < E; e += bpg*256){
    int d = dst[e];
    if (d >= lo && d < hi){
      int pos = rowptr[d] + atomicAdd(&fill[d], 1);
      csr[pos] = src[e];
    }
  }
}

__global__ __launch_bounds__(1024) void k_scan1(const int* __restrict__ counts, int* __restrict__ rowptr,
                                                int* __restrict__ bsum, float* __restrict__ dinv, int N){
  __shared__ int s[1024];
  int t = threadIdx.x, g = blockIdx.x*1024 + t;
  int v = (g < N) ? counts[g] : 0;
  if (g < N) dinv[g] = rsqrtf((float)(v + 1));   // +1 = self-loop
  s[t] = v; __syncthreads();
  for (int off = 1; off < 1024; off <<= 1){
    int u = (t >= off) ? s[t-off] : 0; __syncthreads();
    s[t] += u; __syncthreads();
  }
  if (g < N) rowptr[g] = s[t] - v;
  if (t == 1023) bsum[blockIdx.x] = s[1023];
}

__global__ __launch_bounds__(128) void k_scan2(const int* __restrict__ bsum, int* __restrict__ boff,
                                               int nb, int* __restrict__ rowptr, int N){
  __shared__ int s[128];
  int t = threadIdx.x;
  int v = (t < nb) ? bsum[t] : 0;
  s[t] = v; __syncthreads();
  for (int off = 1; off < 128; off <<= 1){
    int u = (t >= off) ? s[t-off] : 0; __syncthreads();
    s[t] += u; __syncthreads();
  }
  if (t < nb) boff[t] = s[t] - v;
  if (t == 127) rowptr[N] = s[127];
}

__global__ __launch_bounds__(1024) void k_scan3(int* __restrict__ rowptr, const int* __restrict__ boff, int N){
  int g = blockIdx.x*1024 + threadIdx.x;
  if (g < N) rowptr[g] += boff[blockIdx.x];
}

// ---------------- split weights into FRAGMENT-LINEARIZED bf16 hi/lo ----------------
__global__ __launch_bounds__(256) void k_split_w(const float* __restrict__ W1, const float* __restrict__ W2,
                                                 unsigned short* __restrict__ W1h, unsigned short* __restrict__ W1l,
                                                 unsigned short* __restrict__ W2h, unsigned short* __restrict__ W2l,
                                                 int L){
  int idx = blockIdx.x*256 + threadIdx.x;
  int n1 = 64*128;
  if (idx < n1){
    int j = idx & 7, lane = (idx >> 3) & 63, t = idx >> 9;   // t = kc*8+nt, kc<2 (K=64)
    int kc = t >> 3, nt = t & 7;
    int tcol = lane & 15, quad = lane >> 4;
    int k = kc*32 + quad*8 + j, n = nt*16 + tcol;
    float v = W1[k*128 + n];
    unsigned short hi = f2bf(v);
    W1h[idx] = hi; W1l[idx] = f2bf(v - bf2f(hi));
  } else {
    int idx2 = idx - n1;
    if (idx2 >= L*128*128) return;
    int i = idx2 >> 14, r = idx2 & 16383;
    int j = r & 7, lane = (r >> 3) & 63, t = r >> 9;         // t = kc*8+nt, kc<4 (K=128)
    int kc = t >> 3, nt = t & 7;
    int tcol = lane & 15, quad = lane >> 4;
    int k = kc*32 + quad*8 + j, n = nt*16 + tcol;
    float v = W2[(size_t)i*16384 + k*128 + n];
    unsigned short hi = f2bf(v);
    W2h[idx2] = hi; W2l[idx2] = f2bf(v - bf2f(hi));
  }
}

// ---------------- fused layer 1: gather64(x) -> MFMA(W1,b1,relu) -> MFMA(W2_0)*dinv -> pF ----------------
// 512 thr = 8 waves; 64-row tile. Wave w: rows (w>>1)*16, cols (w&1)*64 (nt 0..3). LDS 34.8 KB
// (X 18.4 KB unioned under H 34.8 KB) -> 4 blocks/CU -> 32 waves: gather runs at full fabric rate.
__global__ __launch_bounds__(512) void k_layer1(const float* __restrict__ x, const int* __restrict__ rowptr,
                                                const int* __restrict__ csr, const float* __restrict__ dinv,
                                                const unsigned short* __restrict__ W1h, const unsigned short* __restrict__ W1l,
                                                const float* __restrict__ b1,
                                                const unsigned short* __restrict__ W2h0, const unsigned short* __restrict__ W2l0,
                                                float* __restrict__ pout, int N){
  constexpr int XS = 72, HS = 136;
  __shared__ __align__(16) char smem[64*HS*2*2];            // 34816 B
  unsigned short (*Xh)[XS] = (unsigned short(*)[XS])smem;
  unsigned short (*Xl)[XS] = (unsigned short(*)[XS])(smem + 64*XS*2);
  unsigned short (*Hh)[HS] = (unsigned short(*)[HS])smem;
  unsigned short (*Hl)[HS] = (unsigned short(*)[HS])(smem + 64*HS*2);

  const int tid = threadIdx.x;
  const int node0 = blockIdx.x*64;

  // ---- phase 1: gather raw x (16 lanes/node, 2 iters of 32 nodes) -> split into X ----
  {
    const int nl = tid >> 4;            // 0..31
    const int c  = (tid & 15) * 4;
    const float* xc = x + c;
    #pragma unroll
    for (int it = 0; it < 2; ++it){
      int ln = it*32 + nl;
      int node = node0 + ln;
      if (node < N){
        const float dn = dinv[node];
        float4 s = *(const float4*)(x + (size_t)node*64 + c);
        float ax = dn*s.x, ay = dn*s.y, az = dn*s.z, aw = dn*s.w;
        int e = rowptr[node], end = rowptr[node+1];
        for (; e + 4 <= end; e += 4){
          int s0 = csr[e], s1 = csr[e+1], s2 = csr[e+2], s3 = csr[e+3];
          float d0 = dinv[s0], d1 = dinv[s1], d2 = dinv[s2], d3 = dinv[s3];
          float4 v0 = *(const float4*)(xc + (size_t)s0*64);
          float4 v1 = *(const float4*)(xc + (size_t)s1*64);
          float4 v2 = *(const float4*)(xc + (size_t)s2*64);
          float4 v3 = *(const float4*)(xc + (size_t)s3*64);
          ax += d0*v0.x + d1*v1.x + d2*v2.x + d3*v3.x;
          ay += d0*v0.y + d1*v1.y + d2*v2.y + d3*v3.y;
          az += d0*v0.z + d1*v1.z + d2*v2.z + d3*v3.z;
          aw += d0*v0.w + d1*v1.w + d2*v2.w + d3*v3.w;
        }
        for (; e < end; ++e){
          int s0 = csr[e];
          float d0 = dinv[s0];
          float4 v = *(const float4*)(xc + (size_t)s0*64);
          ax += d0*v.x; ay += d0*v.y; az += d0*v.z; aw += d0*v.w;
        }
        float o[4] = {dn*ax, dn*ay, dn*az, dn*aw};
        ushort4 hh, hl;
        unsigned short* hp = (unsigned short*)&hh;
        unsigned short* lp = (unsigned short*)&hl;
        #pragma unroll
        for (int j = 0; j < 4; ++j){
          unsigned short hi = f2bf(o[j]);
          hp[j] = hi; lp[j] = f2bf(o[j] - bf2f(hi));
        }
        *(ushort4*)&Xh[ln][c] = hh;
        *(ushort4*)&Xl[ln][c] = hl;
      }
    }
  }
  __syncthreads();

  const int wv = tid >> 6, lane = tid & 63, quad = lane >> 4, tcol = lane & 15;
  const int wrow = (wv >> 1) * 16;      // wave's row offset in tile
  const int wcol = (wv & 1) * 64;       // wave's col half

  // ---- phase 2: h1 = x_agg @ W1 (K=64) ----
  f32x4 acc[4];
  #pragma unroll
  for (int t = 0; t < 4; ++t){ acc[t][0]=0.f; acc[t][1]=0.f; acc[t][2]=0.f; acc[t][3]=0.f; }
  #pragma unroll
  for (int kc = 0; kc < 2; ++kc){
    short8v a_h = *(const short8v*)&Xh[wrow + tcol][kc*32 + quad*8];
    short8v a_l = *(const short8v*)&Xl[wrow + tcol][kc*32 + quad*8];
    #pragma unroll
    for (int ntl = 0; ntl < 4; ++ntl){
      int nt = (wv & 1)*4 + ntl;
      const unsigned short* bb = W1h + ((size_t)(kc*8 + nt)*64 + lane)*8;
      const unsigned short* bl = W1l + ((size_t)(kc*8 + nt)*64 + lane)*8;
      short8v b_h = *(const short8v*)bb;
      short8v b_l = *(const short8v*)bl;
      acc[ntl] = __builtin_amdgcn_mfma_f32_16x16x32_bf16(a_h, b_h, acc[ntl], 0, 0, 0);
      acc[ntl] = __builtin_amdgcn_mfma_f32_16x16x32_bf16(a_l, b_h, acc[ntl], 0, 0, 0);
      acc[ntl] = __builtin_amdgcn_mfma_f32_16x16x32_bf16(a_h, b_l, acc[ntl], 0, 0, 0);
    }
  }
  __syncthreads();                      // X fully read -> safe to overwrite with H

  // ---- phase 3: relu(h1 + b1) -> split into H ----
  #pragma unroll
  for (int reg = 0; reg < 4; ++reg){
    int lrow = wrow + quad*4 + reg;
    #pragma unroll
    for (int ntl = 0; ntl < 4; ++ntl){
      int col = wcol + ntl*16 + tcol;
      float o = fmaxf(acc[ntl][reg] + b1[col], 0.f);
      unsigned short hi = f2bf(o);
      Hh[lrow][col] = hi;
      Hl[lrow][col] = f2bf(o - bf2f(hi));
    }
  }
  __syncthreads();

  // ---- phase 4: p = dinv * (h1 @ W2_0) (K=128) ----
  #pragma unroll
  for (int t = 0; t < 4; ++t){ acc[t][0]=0.f; acc[t][1]=0.f; acc[t][2]=0.f; acc[t][3]=0.f; }
  #pragma unroll
  for (int kc = 0; kc < 4; ++kc){
    short8v a_h = *(const short8v*)&Hh[wrow + tcol][kc*32 + quad*8];
    short8v a_l = *(const short8v*)&Hl[wrow + tcol][kc*32 + quad*8];
    #pragma unroll
    for (int ntl = 0; ntl < 4; ++ntl){
      int nt = (wv & 1)*4 + ntl;
      const unsigned short* bb = W2h0 + ((size_t)(kc*8 + nt)*64 + lane)*8;
      const unsigned short* bl = W2l0 + ((size_t)(kc*8 + nt)*64 + lane)*8;
      short8v b_h = *(const short8v*)bb;
      short8v b_l = *(const short8v*)bl;
      acc[ntl] = __builtin_amdgcn_mfma_f32_16x16x32_bf16(a_h, b_h, acc[ntl], 0, 0, 0);
      acc[ntl] = __builtin_amdgcn_mfma_f32_16x16x32_bf16(a_l, b_h, acc[ntl], 0, 0, 0);
      acc[ntl] = __builtin_amdgcn_mfma_f32_16x16x32_bf16(a_h, b_l, acc[ntl], 0, 0, 0);
    }
  }
  #pragma unroll
  for (int reg = 0; reg < 4; ++reg){
    int grow = node0 + wrow + quad*4 + reg;
    if (grow < N){
      float sc = dinv[grow];
      float* op = pout + (size_t)grow*128 + wcol + tcol;
      #pragma unroll
      for (int ntl = 0; ntl < 4; ++ntl) op[ntl*16] = acc[ntl][reg] * sc;
    }
  }
}

// ---------------- fused mid layer: gather128(p)+bias+relu -> MFMA(W2_i)*dinv -> pout ----------------
// 512 thr = 8 waves, 64-row tile, LDS 34.8 KB -> 4 blocks/CU -> 32 waves (gather at full rate).
__global__ __launch_bounds__(512) void k_fuse2(const float* __restrict__ p, const int* __restrict__ rowptr,
                                               const int* __restrict__ csr, const float* __restrict__ dinv,
                                               const float* __restrict__ bias,
                                               const unsigned short* __restrict__ Bh, const unsigned short* __restrict__ Bl,
                                               float* __restrict__ pout, int N){
  constexpr int HS = 136;
  __shared__ __align__(16) char smem[64*HS*2*2];            // 34816 B
  unsigned short (*Hh)[HS] = (unsigned short(*)[HS])smem;
  unsigned short (*Hl)[HS] = (unsigned short(*)[HS])(smem + 64*HS*2);

  const int tid = threadIdx.x;
  const int node0 = blockIdx.x*64;

  // ---- phase 1: gather (32 lanes/node, 4 iters of 16 nodes) + relu(dinv*sum+bias) -> split into H ----
  {
    const int nl = tid >> 5;            // 0..15
    const int c  = (tid & 31) * 4;
    const float* pc = p + c;
    #pragma unroll
    for (int it = 0; it < 4; ++it){
      int ln = it*16 + nl;
      int node = node0 + ln;
      if (node < N){
        int e = rowptr[node], end = rowptr[node+1];
        float4 s = *(const float4*)(p + (size_t)node*128 + c);
        float ax = s.x, ay = s.y, az = s.z, aw = s.w;
        for (; e + 4 <= end; e += 4){
          int s0 = csr[e], s1 = csr[e+1], s2 = csr[e+2], s3 = csr[e+3];
          float4 v0 = *(const float4*)(pc + (size_t)s0*128);
          float4 v1 = *(const float4*)(pc + (size_t)s1*128);
          float4 v2 = *(const float4*)(pc + (size_t)s2*128);
          float4 v3 = *(const float4*)(pc + (size_t)s3*128);
          ax += v0.x+v1.x+v2.x+v3.x; ay += v0.y+v1.y+v2.y+v3.y;
          az += v0.z+v1.z+v2.z+v3.z; aw += v0.w+v1.w+v2.w+v3.w;
        }
        for (; e < end; ++e){
          float4 v = *(const float4*)(pc + (size_t)csr[e]*128);
          ax += v.x; ay += v.y; az += v.z; aw += v.w;
        }
        float d = dinv[node];
        float o[4] = {fmaxf(d*ax + bias[c],   0.f), fmaxf(d*ay + bias[c+1], 0.f),
                      fmaxf(d*az + bias[c+2], 0.f), fmaxf(d*aw + bias[c+3], 0.f)};
        ushort4 hh, hl;
        unsigned short* hp = (unsigned short*)&hh;
        unsigned short* lp = (unsigned short*)&hl;
        #pragma unroll
        for (int j = 0; j < 4; ++j){
          unsigned short hi = f2bf(o[j]);
          hp[j] = hi; lp[j] = f2bf(o[j] - bf2f(hi));
        }
        *(ushort4*)&Hh[ln][c] = hh;
        *(ushort4*)&Hl[ln][c] = hl;
      }
    }
  }
  __syncthreads();

  // ---- phase 2: p' = dinv * (h @ W2_i) (K=128) ----
  const int wv = tid >> 6, lane = tid & 63, quad = lane >> 4, tcol = lane & 15;
  const int wrow = (wv >> 1) * 16;
  const int wcol = (wv & 1) * 64;
  f32x4 acc[4];
  #pragma unroll
  for (int t = 0; t < 4; ++t){ acc[t][0]=0.f; acc[t][1]=0.f; acc[t][2]=0.f; acc[t][3]=0.f; }
  #pragma unroll
  for (int kc = 0; kc < 4; ++kc){
    short8v a_h = *(const short8v*)&Hh[wrow + tcol][kc*32 + quad*8];
    short8v a_l = *(const short8v*)&Hl[wrow + tcol][kc*32 + quad*8];
    #pragma unroll
    for (int ntl = 0; ntl < 4; ++ntl){
      int nt = (wv & 1)*4 + ntl;
      const unsigned short* bb = Bh + ((size_t)(kc*8 + nt)*64 + lane)*8;
      const unsigned short* bl = Bl + ((size_t)(kc*8 + nt)*64 + lane)*8;
      short8v b_h = *(const short8v*)bb;
      short8v b_l = *(const short8v*)bl;
      acc[ntl] = __builtin_amdgcn_mfma_f32_16x16x32_bf16(a_h, b_h, acc[ntl], 0, 0, 0);
      acc[ntl] = __builtin_amdgcn_mfma_f32_16x16x32_bf16(a_l, b_h, acc[ntl], 0, 0, 0);
      acc[ntl] = __builtin_amdgcn_mfma_f32_16x16x32_bf16(a_h, b_l, acc[ntl], 0, 0, 0);
    }
  }
  #pragma unroll
  for (int reg = 0; reg < 4; ++reg){
    int grow = node0 + wrow + quad*4 + reg;
    if (grow < N){
      float sc = dinv[grow];
      float* op = pout + (size_t)grow*128 + wcol + tcol;
      #pragma unroll
      for (int ntl = 0; ntl < 4; ++ntl) op[ntl*16] = acc[ntl][reg] * sc;
    }
  }
}

// ---------------- last 128-wide agg fused with W3 projection (32 lanes/node) ----------------
__global__ __launch_bounds__(256) void k_agg_last(const float* __restrict__ p, const int* __restrict__ rowptr,
                                                  const int* __restrict__ csr, const float* __restrict__ dinv,
                                                  const float* __restrict__ bias, const float* __restrict__ W3,
                                                  float* __restrict__ p5, int N){
  const int tid = threadIdx.x;
  const int node = blockIdx.x*8 + (tid >> 5);
  if (node >= N) return;
  const int c = (tid & 31) * 4;
  const float* pc = p + c;
  int e = rowptr[node], end = rowptr[node+1];
  float4 s = *(const float4*)(p + (size_t)node*128 + c);
  float ax = s.x, ay = s.y, az = s.z, aw = s.w;
  for (; e + 4 <= end; e += 4){
    int s0 = csr[e], s1 = csr[e+1], s2 = csr[e+2], s3 = csr[e+3];
    float4 v0 = *(const float4*)(pc + (size_t)s0*128);
    float4 v1 = *(const float4*)(pc + (size_t)s1*128);
    float4 v2 = *(const float4*)(pc + (size_t)s2*128);
    float4 v3 = *(const float4*)(pc + (size_t)s3*128);
    ax += v0.x+v1.x+v2.x+v3.x; ay += v0.y+v1.y+v2.y+v3.y;
    az += v0.z+v1.z+v2.z+v3.z; aw += v0.w+v1.w+v2.w+v3.w;
  }
  for (; e < end; ++e){
    float4 v = *(const float4*)(pc + (size_t)csr[e]*128);
    ax += v.x; ay += v.y; az += v.z; aw += v.w;
  }
  float d = dinv[node];
  float o0 = fmaxf(d*ax + bias[c],   0.f);
  float o1 = fmaxf(d*ay + bias[c+1], 0.f);
  float o2 = fmaxf(d*az + bias[c+2], 0.f);
  float o3 = fmaxf(d*aw + bias[c+3], 0.f);
  float4 w = *(const float4*)(W3 + c);
  float sdot = o0*w.x + o1*w.y + o2*w.z + o3*w.w;
  #pragma unroll
  for (int m = 16; m >= 1; m >>= 1) sdot += __shfl_xor(sdot, m, 32);
  if ((tid & 31) == 0) p5[node] = d * sdot;
}

// ---------------- final scalar aggregation ----------------
__global__ __launch_bounds__(256) void k_agg1(const float* __restrict__ p5, const int* __restrict__ rowptr,
                                              const int* __restrict__ csr, const float* __restrict__ dinv,
                                              const float* __restrict__ b3, float* __restrict__ out, int N){
  int n = blockIdx.x*256 + threadIdx.x;
  if (n >= N) return;
  int e = rowptr[n], end = rowptr[n+1];
  float acc = p5[n];
  for (; e + 4 <= end; e += 4)
    acc += p5[csr[e]] + p5[csr[e+1]] + p5[csr[e+2]] + p5[csr[e+3]];
  for (; e < end; ++e) acc += p5[csr[e]];
  out[n] = dinv[n]*acc + b3[0];
}

extern "C" void kernel_launch(void* const* d_in, const int* in_sizes, int n_in,
                              void* d_out, int out_size, void* d_ws, size_t ws_size,
                              hipStream_t stream){
  const float* x  = (const float*)d_in[0];
  const int*   ei = (const int*)  d_in[1];
  const float* W1 = (const float*)d_in[2];
  const float* b1 = (const float*)d_in[3];
  const float* W2 = (const float*)d_in[4];
  const float* b2 = (const float*)d_in[5];
  const float* W3 = (const float*)d_in[6];
  const float* b3 = (const float*)d_in[7];
  float* out = (float*)d_out;

  const int N = in_sizes[0] / 64;
  const int E = in_sizes[1] / 2;
  const int L = in_sizes[4] / (128*128);
  const int* src = ei;
  const int* dst = ei + E;

  char* ws = (char*)d_ws;
  size_t off = 0;
  auto alloc = [&](size_t bytes){ void* p = ws + off; off += (bytes + 255) & ~(size_t)255; return p; };
  size_t cntb = ((size_t)N*4 + 255) & ~(size_t)255;
  int*   counts = (int*)  alloc(cntb*2);       // counts + fillc adjacent -> one memset
  int*   fillc  = (int*)((char*)counts + cntb);
  int*   rowptr = (int*)  alloc((size_t)(N+1)*4);
  int*   bsum   = (int*)  alloc(128*4);
  int*   boff   = (int*)  alloc(128*4);
  float* dinv   = (float*)alloc((size_t)N*4);
  float* p5     = (float*)alloc((size_t)N*4);
  int*   csr    = (int*)  alloc((size_t)E*4);
  float* pA     = (float*)alloc((size_t)N*128*4);
  float* pB     = (float*)alloc((size_t)N*128*4);
  unsigned short* W1h = (unsigned short*)alloc(64*128*2);
  unsigned short* W1l = (unsigned short*)alloc(64*128*2);
  unsigned short* W2h = (unsigned short*)alloc((size_t)L*128*128*2);
  unsigned short* W2l = (unsigned short*)alloc((size_t)L*128*128*2);
  (void)ws_size; (void)n_in; (void)out_size;

  hipMemsetAsync(counts, 0, cntb*2, stream);

  k_count_g<<<1024,256,0,stream>>>(dst, counts, E, N);
  int nb = DIV_UP(N,1024);
  k_scan1<<<nb,1024,0,stream>>>(counts, rowptr, bsum, dinv, N);
  k_scan2<<<1,128,0,stream>>>(bsum, boff, nb, rowptr, N);
  k_scan3<<<nb,1024,0,stream>>>(rowptr, boff, N);
  k_fill_g<<<1024,256,0,stream>>>(src, dst, rowptr, fillc, csr, E, N);

  int wtot = 64*128 + L*128*128;
  k_split_w<<<DIV_UP(wtot,256),256,0,stream>>>(W1, W2, W1h, W1l, W2h, W2l, L);

  // fused chain: layer1 (gather64 + W1 + W2_0) -> pA; mid fusions; agg_last; agg1
  k_layer1<<<DIV_UP(N,64),512,0,stream>>>(x, rowptr, csr, dinv, W1h, W1l, b1, W2h, W2l, pA, N);
  float* pin = pA; float* pout = pB;
  for (int i = 1; i < L; ++i){
    k_fuse2<<<DIV_UP(N,64),512,0,stream>>>(pin, rowptr, csr, dinv, b2 + (size_t)(i-1)*128,
                                           W2h + (size_t)i*128*128, W2l + (size_t)i*128*128, pout, N);
    float* t = pin; pin = pout; pout = t;
  }
  k_agg_last<<<DIV_UP(N,8),256,0,stream>>>(pin, rowptr, csr, dinv, b2 + (size_t)(L-1)*128, W3, p5, N);

  k_agg1<<<DIV_UP(N,256),256,0,stream>>>(p5, rowptr, csr, dinv, b3, out, N);
}

// Round 11
// 679.905 us; speedup vs baseline: 1.1325x; 1.0242x over previous
//
#include <hip/hip_runtime.h>
#include <hip/hip_bf16.h>

#define DIV_UP(a,b) (((a)+(b)-1)/(b))

typedef __attribute__((ext_vector_type(8))) short short8v;
typedef __attribute__((ext_vector_type(4))) float f32x4;

__device__ inline unsigned short f2bf(float f){
  unsigned u = __float_as_uint(f);
  u += 0x7FFFu + ((u >> 16) & 1u);          // RNE
  return (unsigned short)(u >> 16);
}
__device__ inline float bf2f(unsigned short h){ return __uint_as_float(((unsigned)h) << 16); }

// ---------------- preprocessing ----------------
// Replicated histogram: group g = blockIdx&7 (XCD heuristic) processes contiguous E/8 edge
// slice into its own counts8[g] replica -> dst read once, atomics L2-local.
__global__ __launch_bounds__(256) void k_count_r(const int* __restrict__ dst, int* __restrict__ counts8,
                                                 int E, int N){
  const int g   = blockIdx.x & 7;
  const int bi  = blockIdx.x >> 3;
  const int bpg = gridDim.x >> 3;
  const int chunkE = (E + 7) >> 3;
  const int lo = g*chunkE;
  const int hi = min(lo + chunkE, E);
  int* base = counts8 + (size_t)g*N;
  for (int e = lo + bi*256 + threadIdx.x; e < hi; e += bpg*256)
    atomicAdd(&base[dst[e]], 1);
}

__global__ __launch_bounds__(256) void k_fill_g(const int* __restrict__ src, const int* __restrict__ dst,
                                                const int* __restrict__ rowptr, int* __restrict__ fill,
                                                int* __restrict__ csr, int E, int N){
  const int g   = blockIdx.x & 7;
  const int bi  = blockIdx.x >> 3;
  const int bpg = gridDim.x >> 3;
  const int chunk = (N + 7) >> 3;
  const int lo = g*chunk;
  const int hi = min(lo + chunk, N);
  for (int e = bi*256 + threadIdx.x; e < E; e += bpg*256){
    int d = dst[e];
    if (d >= lo && d < hi){
      int pos = rowptr[d] + atomicAdd(&fill[d], 1);
      csr[pos] = src[e];
    }
  }
}

__global__ __launch_bounds__(1024) void k_scan1(const int* __restrict__ counts8, int* __restrict__ rowptr,
                                                int* __restrict__ bsum, float* __restrict__ dinv, int N){
  __shared__ int s[1024];
  int t = threadIdx.x, g = blockIdx.x*1024 + t;
  int v = 0;
  if (g < N){
    #pragma unroll
    for (int j = 0; j < 8; ++j) v += counts8[(size_t)j*N + g];
    dinv[g] = rsqrtf((float)(v + 1));   // +1 = self-loop
  }
  s[t] = v; __syncthreads();
  for (int off = 1; off < 1024; off <<= 1){
    int u = (t >= off) ? s[t-off] : 0; __syncthreads();
    s[t] += u; __syncthreads();
  }
  if (g < N) rowptr[g] = s[t] - v;
  if (t == 1023) bsum[blockIdx.x] = s[1023];
}

__global__ __launch_bounds__(128) void k_scan2(const int* __restrict__ bsum, int* __restrict__ boff,
                                               int nb, int* __restrict__ rowptr, int N){
  __shared__ int s[128];
  int t = threadIdx.x;
  int v = (t < nb) ? bsum[t] : 0;
  s[t] = v; __syncthreads();
  for (int off = 1; off < 128; off <<= 1){
    int u = (t >= off) ? s[t-off] : 0; __syncthreads();
    s[t] += u; __syncthreads();
  }
  if (t < nb) boff[t] = s[t] - v;
  if (t == 127) rowptr[N] = s[127];
}

__global__ __launch_bounds__(1024) void k_scan3(int* __restrict__ rowptr, const int* __restrict__ boff, int N){
  int g = blockIdx.x*1024 + threadIdx.x;
  if (g < N) rowptr[g] += boff[blockIdx.x];
}

// ---------------- split weights into FRAGMENT-LINEARIZED bf16 hi/lo ----------------
__global__ __launch_bounds__(256) void k_split_w(const float* __restrict__ W1, const float* __restrict__ W2,
                                                 unsigned short* __restrict__ W1h, unsigned short* __restrict__ W1l,
                                                 unsigned short* __restrict__ W2h, unsigned short* __restrict__ W2l,
                                                 int L){
  int idx = blockIdx.x*256 + threadIdx.x;
  int n1 = 64*128;
  if (idx < n1){
    int j = idx & 7, lane = (idx >> 3) & 63, t = idx >> 9;   // t = kc*8+nt, kc<2 (K=64)
    int kc = t >> 3, nt = t & 7;
    int tcol = lane & 15, quad = lane >> 4;
    int k = kc*32 + quad*8 + j, n = nt*16 + tcol;
    float v = W1[k*128 + n];
    unsigned short hi = f2bf(v);
    W1h[idx] = hi; W1l[idx] = f2bf(v - bf2f(hi));
  } else {
    int idx2 = idx - n1;
    if (idx2 >= L*128*128) return;
    int i = idx2 >> 14, r = idx2 & 16383;
    int j = r & 7, lane = (r >> 3) & 63, t = r >> 9;         // t = kc*8+nt, kc<4 (K=128)
    int kc = t >> 3, nt = t & 7;
    int tcol = lane & 15, quad = lane >> 4;
    int k = kc*32 + quad*8 + j, n = nt*16 + tcol;
    float v = W2[(size_t)i*16384 + k*128 + n];
    unsigned short hi = f2bf(v);
    W2h[idx2] = hi; W2l[idx2] = f2bf(v - bf2f(hi));
  }
}

// ---------------- fused layer 1: gather64(x) -> MFMA(W1,b1,relu) -> MFMA(W2_0)*dinv ----------------
// 256 thr = 4 waves, 32-row tile, LDS 17.4 KB -> 8 blocks/CU (32 waves): fine phase interleave.
// Wave w: rows (w>>1)*16, cols (w&1)*64.
__global__ __launch_bounds__(256) void k_layer1(const float* __restrict__ x, const int* __restrict__ rowptr,
                                                const int* __restrict__ csr, const float* __restrict__ dinv,
                                                const unsigned short* __restrict__ W1h, const unsigned short* __restrict__ W1l,
                                                const float* __restrict__ b1,
                                                const unsigned short* __restrict__ W2h0, const unsigned short* __restrict__ W2l0,
                                                float* __restrict__ pout, int N){
  constexpr int XS = 72, HS = 136;
  __shared__ __align__(16) char smem[32*HS*2*2];            // 17408 B
  unsigned short (*Xh)[XS] = (unsigned short(*)[XS])smem;
  unsigned short (*Xl)[XS] = (unsigned short(*)[XS])(smem + 32*XS*2);
  unsigned short (*Hh)[HS] = (unsigned short(*)[HS])smem;
  unsigned short (*Hl)[HS] = (unsigned short(*)[HS])(smem + 32*HS*2);

  const int tid = threadIdx.x;
  const int node0 = blockIdx.x*32;

  // ---- phase 1: gather raw x (16 lanes/node, 2 iters of 16 nodes) -> split into X ----
  {
    const int nl = tid >> 4;            // 0..15
    const int c  = (tid & 15) * 4;
    const float* xc = x + c;
    #pragma unroll
    for (int it = 0; it < 2; ++it){
      int ln = it*16 + nl;
      int node = node0 + ln;
      if (node < N){
        const float dn = dinv[node];
        float4 s = *(const float4*)(x + (size_t)node*64 + c);
        float ax = dn*s.x, ay = dn*s.y, az = dn*s.z, aw = dn*s.w;
        int e = rowptr[node], end = rowptr[node+1];
        for (; e + 4 <= end; e += 4){
          int s0 = csr[e], s1 = csr[e+1], s2 = csr[e+2], s3 = csr[e+3];
          float d0 = dinv[s0], d1 = dinv[s1], d2 = dinv[s2], d3 = dinv[s3];
          float4 v0 = *(const float4*)(xc + (size_t)s0*64);
          float4 v1 = *(const float4*)(xc + (size_t)s1*64);
          float4 v2 = *(const float4*)(xc + (size_t)s2*64);
          float4 v3 = *(const float4*)(xc + (size_t)s3*64);
          ax += d0*v0.x + d1*v1.x + d2*v2.x + d3*v3.x;
          ay += d0*v0.y + d1*v1.y + d2*v2.y + d3*v3.y;
          az += d0*v0.z + d1*v1.z + d2*v2.z + d3*v3.z;
          aw += d0*v0.w + d1*v1.w + d2*v2.w + d3*v3.w;
        }
        for (; e < end; ++e){
          int s0 = csr[e];
          float d0 = dinv[s0];
          float4 v = *(const float4*)(xc + (size_t)s0*64);
          ax += d0*v.x; ay += d0*v.y; az += d0*v.z; aw += d0*v.w;
        }
        float o[4] = {dn*ax, dn*ay, dn*az, dn*aw};
        ushort4 hh, hl;
        unsigned short* hp = (unsigned short*)&hh;
        unsigned short* lp = (unsigned short*)&hl;
        #pragma unroll
        for (int j = 0; j < 4; ++j){
          unsigned short hi = f2bf(o[j]);
          hp[j] = hi; lp[j] = f2bf(o[j] - bf2f(hi));
        }
        *(ushort4*)&Xh[ln][c] = hh;
        *(ushort4*)&Xl[ln][c] = hl;
      }
    }
  }
  __syncthreads();

  const int wv = tid >> 6, lane = tid & 63, quad = lane >> 4, tcol = lane & 15;
  const int wrow = (wv >> 1) * 16;
  const int wcol = (wv & 1) * 64;

  // ---- phase 2: h1 = x_agg @ W1 (K=64) ----
  f32x4 acc[4];
  #pragma unroll
  for (int t = 0; t < 4; ++t){ acc[t][0]=0.f; acc[t][1]=0.f; acc[t][2]=0.f; acc[t][3]=0.f; }
  #pragma unroll
  for (int kc = 0; kc < 2; ++kc){
    short8v a_h = *(const short8v*)&Xh[wrow + tcol][kc*32 + quad*8];
    short8v a_l = *(const short8v*)&Xl[wrow + tcol][kc*32 + quad*8];
    #pragma unroll
    for (int ntl = 0; ntl < 4; ++ntl){
      int nt = (wv & 1)*4 + ntl;
      short8v b_h = *(const short8v*)(W1h + ((size_t)(kc*8 + nt)*64 + lane)*8);
      short8v b_l = *(const short8v*)(W1l + ((size_t)(kc*8 + nt)*64 + lane)*8);
      acc[ntl] = __builtin_amdgcn_mfma_f32_16x16x32_bf16(a_h, b_h, acc[ntl], 0, 0, 0);
      acc[ntl] = __builtin_amdgcn_mfma_f32_16x16x32_bf16(a_l, b_h, acc[ntl], 0, 0, 0);
      acc[ntl] = __builtin_amdgcn_mfma_f32_16x16x32_bf16(a_h, b_l, acc[ntl], 0, 0, 0);
    }
  }
  __syncthreads();                      // X fully read -> overwrite with H

  // ---- phase 3: relu(h1 + b1) -> split into H ----
  #pragma unroll
  for (int reg = 0; reg < 4; ++reg){
    int lrow = wrow + quad*4 + reg;
    #pragma unroll
    for (int ntl = 0; ntl < 4; ++ntl){
      int col = wcol + ntl*16 + tcol;
      float o = fmaxf(acc[ntl][reg] + b1[col], 0.f);
      unsigned short hi = f2bf(o);
      Hh[lrow][col] = hi;
      Hl[lrow][col] = f2bf(o - bf2f(hi));
    }
  }
  __syncthreads();

  // ---- phase 4: p = dinv * (h1 @ W2_0) (K=128) ----
  #pragma unroll
  for (int t = 0; t < 4; ++t){ acc[t][0]=0.f; acc[t][1]=0.f; acc[t][2]=0.f; acc[t][3]=0.f; }
  #pragma unroll
  for (int kc = 0; kc < 4; ++kc){
    short8v a_h = *(const short8v*)&Hh[wrow + tcol][kc*32 + quad*8];
    short8v a_l = *(const short8v*)&Hl[wrow + tcol][kc*32 + quad*8];
    #pragma unroll
    for (int ntl = 0; ntl < 4; ++ntl){
      int nt = (wv & 1)*4 + ntl;
      short8v b_h = *(const short8v*)(W2h0 + ((size_t)(kc*8 + nt)*64 + lane)*8);
      short8v b_l = *(const short8v*)(W2l0 + ((size_t)(kc*8 + nt)*64 + lane)*8);
      acc[ntl] = __builtin_amdgcn_mfma_f32_16x16x32_bf16(a_h, b_h, acc[ntl], 0, 0, 0);
      acc[ntl] = __builtin_amdgcn_mfma_f32_16x16x32_bf16(a_l, b_h, acc[ntl], 0, 0, 0);
      acc[ntl] = __builtin_amdgcn_mfma_f32_16x16x32_bf16(a_h, b_l, acc[ntl], 0, 0, 0);
    }
  }
  #pragma unroll
  for (int reg = 0; reg < 4; ++reg){
    int grow = node0 + wrow + quad*4 + reg;
    if (grow < N){
      float sc = dinv[grow];
      float* op = pout + (size_t)grow*128 + wcol + tcol;
      #pragma unroll
      for (int ntl = 0; ntl < 4; ++ntl) op[ntl*16] = acc[ntl][reg] * sc;
    }
  }
}

// ---------------- fused mid layer: gather128(p)+bias+relu -> MFMA(W2_i)*dinv -> pout ----------------
// 256 thr = 4 waves, 32-row tile, LDS 17.4 KB -> 8 blocks/CU (32 waves).
__global__ __launch_bounds__(256) void k_fuse2(const float* __restrict__ p, const int* __restrict__ rowptr,
                                               const int* __restrict__ csr, const float* __restrict__ dinv,
                                               const float* __restrict__ bias,
                                               const unsigned short* __restrict__ Bh, const unsigned short* __restrict__ Bl,
                                               float* __restrict__ pout, int N){
  constexpr int HS = 136;
  __shared__ __align__(16) char smem[32*HS*2*2];            // 17408 B
  unsigned short (*Hh)[HS] = (unsigned short(*)[HS])smem;
  unsigned short (*Hl)[HS] = (unsigned short(*)[HS])(smem + 32*HS*2);

  const int tid = threadIdx.x;
  const int node0 = blockIdx.x*32;

  // ---- phase 1: gather (32 lanes/node, 4 iters of 8 nodes) + relu(dinv*sum+bias) -> split into H ----
  {
    const int nl = tid >> 5;            // 0..7
    const int c  = (tid & 31) * 4;
    const float* pc = p + c;
    #pragma unroll
    for (int it = 0; it < 4; ++it){
      int ln = it*8 + nl;
      int node = node0 + ln;
      if (node < N){
        int e = rowptr[node], end = rowptr[node+1];
        float4 s = *(const float4*)(p + (size_t)node*128 + c);
        float ax = s.x, ay = s.y, az = s.z, aw = s.w;
        for (; e + 4 <= end; e += 4){
          int s0 = csr[e], s1 = csr[e+1], s2 = csr[e+2], s3 = csr[e+3];
          float4 v0 = *(const float4*)(pc + (size_t)s0*128);
          float4 v1 = *(const float4*)(pc + (size_t)s1*128);
          float4 v2 = *(const float4*)(pc + (size_t)s2*128);
          float4 v3 = *(const float4*)(pc + (size_t)s3*128);
          ax += v0.x+v1.x+v2.x+v3.x; ay += v0.y+v1.y+v2.y+v3.y;
          az += v0.z+v1.z+v2.z+v3.z; aw += v0.w+v1.w+v2.w+v3.w;
        }
        for (; e < end; ++e){
          float4 v = *(const float4*)(pc + (size_t)csr[e]*128);
          ax += v.x; ay += v.y; az += v.z; aw += v.w;
        }
        float d = dinv[node];
        float o[4] = {fmaxf(d*ax + bias[c],   0.f), fmaxf(d*ay + bias[c+1], 0.f),
                      fmaxf(d*az + bias[c+2], 0.f), fmaxf(d*aw + bias[c+3], 0.f)};
        ushort4 hh, hl;
        unsigned short* hp = (unsigned short*)&hh;
        unsigned short* lp = (unsigned short*)&hl;
        #pragma unroll
        for (int j = 0; j < 4; ++j){
          unsigned short hi = f2bf(o[j]);
          hp[j] = hi; lp[j] = f2bf(o[j] - bf2f(hi));
        }
        *(ushort4*)&Hh[ln][c] = hh;
        *(ushort4*)&Hl[ln][c] = hl;
      }
    }
  }
  __syncthreads();

  // ---- phase 2: p' = dinv * (h @ W2_i) (K=128) ----
  const int wv = tid >> 6, lane = tid & 63, quad = lane >> 4, tcol = lane & 15;
  const int wrow = (wv >> 1) * 16;
  const int wcol = (wv & 1) * 64;
  f32x4 acc[4];
  #pragma unroll
  for (int t = 0; t < 4; ++t){ acc[t][0]=0.f; acc[t][1]=0.f; acc[t][2]=0.f; acc[t][3]=0.f; }
  #pragma unroll
  for (int kc = 0; kc < 4; ++kc){
    short8v a_h = *(const short8v*)&Hh[wrow + tcol][kc*32 + quad*8];
    short8v a_l = *(const short8v*)&Hl[wrow + tcol][kc*32 + quad*8];
    #pragma unroll
    for (int ntl = 0; ntl < 4; ++ntl){
      int nt = (wv & 1)*4 + ntl;
      short8v b_h = *(const short8v*)(Bh + ((size_t)(kc*8 + nt)*64 + lane)*8);
      short8v b_l = *(const short8v*)(Bl + ((size_t)(kc*8 + nt)*64 + lane)*8);
      acc[ntl] = __builtin_amdgcn_mfma_f32_16x16x32_bf16(a_h, b_h, acc[ntl], 0, 0, 0);
      acc[ntl] = __builtin_amdgcn_mfma_f32_16x16x32_bf16(a_l, b_h, acc[ntl], 0, 0, 0);
      acc[ntl] = __builtin_amdgcn_mfma_f32_16x16x32_bf16(a_h, b_l, acc[ntl], 0, 0, 0);
    }
  }
  #pragma unroll
  for (int reg = 0; reg < 4; ++reg){
    int grow = node0 + wrow + quad*4 + reg;
    if (grow < N){
      float sc = dinv[grow];
      float* op = pout + (size_t)grow*128 + wcol + tcol;
      #pragma unroll
      for (int ntl = 0; ntl < 4; ++ntl) op[ntl*16] = acc[ntl][reg] * sc;
    }
  }
}

// ---------------- last 128-wide agg fused with W3 projection (32 lanes/node) ----------------
__global__ __launch_bounds__(256) void k_agg_last(const float* __restrict__ p, const int* __restrict__ rowptr,
                                                  const int* __restrict__ csr, const float* __restrict__ dinv,
                                                  const float* __restrict__ bias, const float* __restrict__ W3,
                                                  float* __restrict__ p5, int N){
  const int tid = threadIdx.x;
  const int node = blockIdx.x*8 + (tid >> 5);
  if (node >= N) return;
  const int c = (tid & 31) * 4;
  const float* pc = p + c;
  int e = rowptr[node], end = rowptr[node+1];
  float4 s = *(const float4*)(p + (size_t)node*128 + c);
  float ax = s.x, ay = s.y, az = s.z, aw = s.w;
  for (; e + 4 <= end; e += 4){
    int s0 = csr[e], s1 = csr[e+1], s2 = csr[e+2], s3 = csr[e+3];
    float4 v0 = *(const float4*)(pc + (size_t)s0*128);
    float4 v1 = *(const float4*)(pc + (size_t)s1*128);
    float4 v2 = *(const float4*)(pc + (size_t)s2*128);
    float4 v3 = *(const float4*)(pc + (size_t)s3*128);
    ax += v0.x+v1.x+v2.x+v3.x; ay += v0.y+v1.y+v2.y+v3.y;
    az += v0.z+v1.z+v2.z+v3.z; aw += v0.w+v1.w+v2.w+v3.w;
  }
  for (; e < end; ++e){
    float4 v = *(const float4*)(pc + (size_t)csr[e]*128);
    ax += v.x; ay += v.y; az += v.z; aw += v.w;
  }
  float d = dinv[node];
  float o0 = fmaxf(d*ax + bias[c],   0.f);
  float o1 = fmaxf(d*ay + bias[c+1], 0.f);
  float o2 = fmaxf(d*az + bias[c+2], 0.f);
  float o3 = fmaxf(d*aw + bias[c+3], 0.f);
  float4 w = *(const float4*)(W3 + c);
  float sdot = o0*w.x + o1*w.y + o2*w.z + o3*w.w;
  #pragma unroll
  for (int m = 16; m >= 1; m >>= 1) sdot += __shfl_xor(sdot, m, 32);
  if ((tid & 31) == 0) p5[node] = d * sdot;
}

// ---------------- final scalar aggregation ----------------
__global__ __launch_bounds__(256) void k_agg1(const float* __restrict__ p5, const int* __restrict__ rowptr,
                                              const int* __restrict__ csr, const float* __restrict__ dinv,
                                              const float* __restrict__ b3, float* __restrict__ out, int N){
  int n = blockIdx.x*256 + threadIdx.x;
  if (n >= N) return;
  int e = rowptr[n], end = rowptr[n+1];
  float acc = p5[n];
  for (; e + 4 <= end; e += 4)
    acc += p5[csr[e]] + p5[csr[e+1]] + p5[csr[e+2]] + p5[csr[e+3]];
  for (; e < end; ++e) acc += p5[csr[e]];
  out[n] = dinv[n]*acc + b3[0];
}

extern "C" void kernel_launch(void* const* d_in, const int* in_sizes, int n_in,
                              void* d_out, int out_size, void* d_ws, size_t ws_size,
                              hipStream_t stream){
  const float* x  = (const float*)d_in[0];
  const int*   ei = (const int*)  d_in[1];
  const float* W1 = (const float*)d_in[2];
  const float* b1 = (const float*)d_in[3];
  const float* W2 = (const float*)d_in[4];
  const float* b2 = (const float*)d_in[5];
  const float* W3 = (const float*)d_in[6];
  const float* b3 = (const float*)d_in[7];
  float* out = (float*)d_out;

  const int N = in_sizes[0] / 64;
  const int E = in_sizes[1] / 2;
  const int L = in_sizes[4] / (128*128);
  const int* src = ei;
  const int* dst = ei + E;

  char* ws = (char*)d_ws;
  size_t off = 0;
  auto alloc = [&](size_t bytes){ void* p = ws + off; off += (bytes + 255) & ~(size_t)255; return p; };
  size_t c8b  = (((size_t)N*8*4) + 255) & ~(size_t)255;
  size_t cntb = ((size_t)N*4 + 255) & ~(size_t)255;
  int*   counts8 = (int*)alloc(c8b + cntb);    // counts8 + fillc adjacent -> one memset
  int*   fillc   = (int*)((char*)counts8 + c8b);
  int*   rowptr = (int*)  alloc((size_t)(N+1)*4);
  int*   bsum   = (int*)  alloc(128*4);
  int*   boff   = (int*)  alloc(128*4);
  float* dinv   = (float*)alloc((size_t)N*4);
  float* p5     = (float*)alloc((size_t)N*4);
  int*   csr    = (int*)  alloc((size_t)E*4);
  float* pA     = (float*)alloc((size_t)N*128*4);
  float* pB     = (float*)alloc((size_t)N*128*4);
  unsigned short* W1h = (unsigned short*)alloc(64*128*2);
  unsigned short* W1l = (unsigned short*)alloc(64*128*2);
  unsigned short* W2h = (unsigned short*)alloc((size_t)L*128*128*2);
  unsigned short* W2l = (unsigned short*)alloc((size_t)L*128*128*2);
  (void)ws_size; (void)n_in; (void)out_size;

  hipMemsetAsync(counts8, 0, c8b + cntb, stream);

  k_count_r<<<1024,256,0,stream>>>(dst, counts8, E, N);
  int nb = DIV_UP(N,1024);
  k_scan1<<<nb,1024,0,stream>>>(counts8, rowptr, bsum, dinv, N);
  k_scan2<<<1,128,0,stream>>>(bsum, boff, nb, rowptr, N);
  k_scan3<<<nb,1024,0,stream>>>(rowptr, boff, N);
  k_fill_g<<<1024,256,0,stream>>>(src, dst, rowptr, fillc, csr, E, N);

  int wtot = 64*128 + L*128*128;
  k_split_w<<<DIV_UP(wtot,256),256,0,stream>>>(W1, W2, W1h, W1l, W2h, W2l, L);

  // fused chain: layer1 (gather64 + W1 + W2_0) -> pA; mid fusions; agg_last; agg1
  k_layer1<<<DIV_UP(N,32),256,0,stream>>>(x, rowptr, csr, dinv, W1h, W1l, b1, W2h, W2l, pA, N);
  float* pin = pA; float* pout = pB;
  for (int i = 1; i < L; ++i){
    k_fuse2<<<DIV_UP(N,32),256,0,stream>>>(pin, rowptr, csr, dinv, b2 + (size_t)(i-1)*128,
                                           W2h + (size_t)i*128*128, W2l + (size_t)i*128*128, pout, N);
    float* t = pin; pin = pout; pout = t;
  }
  k_agg_last<<<DIV_UP(N,8),256,0,stream>>>(pin, rowptr, csr, dinv, b2 + (size_t)(L-1)*128, W3, p5, N);

  k_agg1<<<DIV_UP(N,256),256,0,stream>>>(p5, rowptr, csr, dinv, b3, out, N);
}